// Round 1
// baseline (516.393 us; speedup 1.0000x reference)
//
#include <hip/hip_runtime.h>
#include <hip/hip_bf16.h>

#define D_MODEL 512
#define SEQ_L   2048
#define NBATCH  4
#define BLROWS  8192
#define LOG2E_F 1.4426950408889634f
#define BN_EPS_F 1e-5f

typedef __attribute__((ext_vector_type(8))) short bf16x8;
typedef __attribute__((ext_vector_type(4))) float f32x4;

__device__ __forceinline__ unsigned short f2bf(float f){
  union { float f; unsigned u; } x; x.f = f;
  return (unsigned short)((x.u + 0x7fffu + ((x.u >> 16) & 1u)) >> 16);
}
__device__ __forceinline__ unsigned pack2bf(float a, float b){
  return (unsigned)f2bf(a) | ((unsigned)f2bf(b) << 16);
}
__device__ __forceinline__ f32x4 mfma16(bf16x8 a, bf16x8 b, f32x4 c){
  return __builtin_amdgcn_mfma_f32_16x16x32_bf16(a, b, c, 0, 0, 0);
}
__device__ __forceinline__ bf16x8 ldb8(const unsigned short* p){
  return *reinterpret_cast<const bf16x8*>(p);
}

// ---------------- elementwise prep ----------------
__global__ void k_cast(const float* __restrict__ src, unsigned short* __restrict__ dst,
                       int n, float scale){
  int i = (blockIdx.x * blockDim.x + threadIdx.x) * 4;
  if (i >= n) return;
  float4 v = *reinterpret_cast<const float4*>(src + i);
  uint2 o;
  o.x = pack2bf(v.x * scale, v.y * scale);
  o.y = pack2bf(v.z * scale, v.w * scale);
  *reinterpret_cast<uint2*>(dst + i) = o;
}

// A_cat[o][ch] (512x1024): ch<512 -> conv5 block (BN ch 512+ch), else conv3 block (BN ch-512)
__global__ void k_acat(const float* __restrict__ wkl, const float* __restrict__ gamma,
                       const float* __restrict__ var, unsigned short* __restrict__ Acat){
  int idx = blockIdx.x * blockDim.x + threadIdx.x;  // 512*1024
  int o = idx >> 10, ch = idx & 1023;
  int c = (ch < 512) ? (512 + ch) : (ch - 512);
  float a = gamma[c] * rsqrtf(var[c] + BN_EPS_F);
  Acat[idx] = f2bf(wkl[o * 1024 + c] * a);
}

// Bcat[t][ci][ch] (5x512x1024): ch<512 -> w5[ch][ci][t]; else w3[ch-512][ci][t-1] (t in 1..3) else 0
__global__ void k_bcat(const float* __restrict__ w3, const float* __restrict__ w5,
                       unsigned short* __restrict__ Bcat){
  int idx = blockIdx.x * blockDim.x + threadIdx.x;  // 5*512*1024
  int t = idx >> 19; int r = idx & 524287;
  int ci = r >> 10, ch = r & 1023;
  float v;
  if (ch < 512) v = w5[ch * 2560 + ci * 5 + t];
  else {
    int c3 = ch - 512;
    v = (t >= 1 && t <= 3) ? w3[c3 * 1536 + ci * 3 + (t - 1)] : 0.0f;
  }
  Bcat[idx] = f2bf(v);
}

__global__ void k_beff(const float* __restrict__ wkl, const float* __restrict__ gamma,
                       const float* __restrict__ beta, const float* __restrict__ mean,
                       const float* __restrict__ var, const float* __restrict__ cb3,
                       const float* __restrict__ cb5, const float* __restrict__ bkl,
                       float* __restrict__ beff){
  int o = blockIdx.x * blockDim.x + threadIdx.x;
  if (o >= 512) return;
  float acc = bkl[o];
  for (int c = 0; c < 1024; ++c){
    float a = gamma[c] * rsqrtf(var[c] + BN_EPS_F);
    float cb = (c < 512) ? cb3[c] : cb5[c - 512];
    acc += wkl[o * 1024 + c] * (a * cb + beta[c] - a * mean[c]);
  }
  beff[o] = acc;
}

// ---------------- GEMM: C[m,n] = sum_k A[m,k]*B[n,k] (+bias[n]) ----------------
// MODE 0: bf16 out. MODE 1: f32 out. MODE 2: fused-conv KL (A rows shifted by t-2, B=Weff[t]).
template<int MODE>
__global__ __launch_bounds__(256, 2) void k_gemm(
    const unsigned short* __restrict__ A, const unsigned short* __restrict__ Bm,
    void* __restrict__ Cp, const float* __restrict__ bias, float bias_scale,
    int M, int N, int K, int lda, int ldb, int ldc,
    long sBz, long sCz, const unsigned short* __restrict__ zeros)
{
  __shared__ unsigned short As[128 * 64];
  __shared__ unsigned short Bs[128 * 64];
  const int m0 = blockIdx.x * 128, n0 = blockIdx.y * 128;
  const unsigned short* Bz = Bm + (long)blockIdx.z * sBz;
  const int tid = threadIdx.x, wid = tid >> 6, lane = tid & 63;
  const int l15 = lane & 15, hq = lane >> 4;
  const int wr = wid >> 1, wc = wid & 1;
  f32x4 acc[4][4];
#pragma unroll
  for (int m = 0; m < 4; ++m)
#pragma unroll
    for (int n = 0; n < 4; ++n) acc[m][n] = f32x4{0.f, 0.f, 0.f, 0.f};
  const int nkt = K >> 6;
  const int soff = tid * 8;            // elem offset in LDS tile
  const int srow = tid >> 3;           // 0..31
  const int scol = (tid & 7) * 8;      // 0..56
  for (int kt = 0; kt < nkt; ++kt){
    __syncthreads();
    bf16x8 va[4], vb[4];
    if (MODE == 2){
      const int t = kt >> 3; const int ci0 = (kt & 7) << 6;
#pragma unroll
      for (int i = 0; i < 4; ++i){
        int row = srow + i * 32;
        int gr = m0 + row;
        int sl = (gr & (SEQ_L - 1)) + t - 2;
        const unsigned short* sp = ((unsigned)sl < (unsigned)SEQ_L)
            ? (A + (long)(gr + t - 2) * lda + ci0 + scol) : zeros;
        va[i] = ldb8(sp);
        vb[i] = ldb8(Bz + (long)t * 262144 + (long)(n0 + row) * ldb + ci0 + scol);
      }
    } else {
      const int k0 = kt << 6;
#pragma unroll
      for (int i = 0; i < 4; ++i){
        int row = srow + i * 32;
        va[i] = ldb8(A + (long)(m0 + row) * lda + k0 + scol);
        vb[i] = ldb8(Bz + (long)(n0 + row) * ldb + k0 + scol);
      }
    }
#pragma unroll
    for (int i = 0; i < 4; ++i){
      *reinterpret_cast<bf16x8*>(As + soff + i * 2048) = va[i];
      *reinterpret_cast<bf16x8*>(Bs + soff + i * 2048) = vb[i];
    }
    __syncthreads();
#pragma unroll
    for (int ks = 0; ks < 2; ++ks){
      const int kb = ks * 32 + 8 * hq;
      bf16x8 af[4], bfr[4];
#pragma unroll
      for (int m = 0; m < 4; ++m) af[m] = ldb8(As + (wr * 64 + m * 16 + l15) * 64 + kb);
#pragma unroll
      for (int n = 0; n < 4; ++n) bfr[n] = ldb8(Bs + (wc * 64 + n * 16 + l15) * 64 + kb);
#pragma unroll
      for (int m = 0; m < 4; ++m)
#pragma unroll
        for (int n = 0; n < 4; ++n) acc[m][n] = mfma16(af[m], bfr[n], acc[m][n]);
    }
  }
  const int crow0 = m0 + wr * 64, ccol0 = n0 + wc * 64;
#pragma unroll
  for (int n = 0; n < 4; ++n){
    int col = ccol0 + n * 16 + l15;
    float bv = bias ? bias[col] * bias_scale : 0.f;
#pragma unroll
    for (int m = 0; m < 4; ++m){
      int rowb = crow0 + m * 16 + 4 * hq;
#pragma unroll
      for (int r = 0; r < 4; ++r){
        float v = acc[m][n][r] + bv;
        long off = (long)(rowb + r) * ldc + col + (long)blockIdx.z * sCz;
        if (MODE == 1) ((float*)Cp)[off] = v;
        else ((unsigned short*)Cp)[off] = f2bf(v);
      }
    }
  }
}

// ---------------- V transpose: V[b][l][d] -> Vt[b][d][l] ----------------
__global__ __launch_bounds__(256) void k_transpose(const unsigned short* __restrict__ V,
                                                   unsigned short* __restrict__ Vt){
  __shared__ unsigned short t_lds[64][72];
  const int l0 = blockIdx.x * 64, d0 = blockIdx.y * 64, b = blockIdx.z;
  const int tid = threadIdx.x;
  const int rr = tid >> 3, cc = (tid & 7) * 8;
#pragma unroll
  for (int p = 0; p < 2; ++p){
    int r = rr + p * 32;
    bf16x8 v = ldb8(V + ((long)(b * SEQ_L + l0 + r)) * D_MODEL + d0 + cc);
#pragma unroll
    for (int j = 0; j < 8; ++j) t_lds[r][cc + j] = (unsigned short)v[j];
  }
  __syncthreads();
#pragma unroll
  for (int p = 0; p < 2; ++p){
    int dr = rr + p * 32;
    bf16x8 o;
#pragma unroll
    for (int j = 0; j < 8; ++j) o[j] = (short)t_lds[cc + j][dr];
    *reinterpret_cast<bf16x8*>(Vt + ((long)(b * D_MODEL + d0 + dr)) * SEQ_L + l0 + cc) = o;
  }
}

// ---------------- flash attention (two score paths, shared V) ----------------
__global__ __launch_bounds__(256, 2) void k_attn(
    const unsigned short* __restrict__ Q, const unsigned short* __restrict__ KLp,
    const unsigned short* __restrict__ KGp, const unsigned short* __restrict__ Vt,
    unsigned short* __restrict__ X)
{
  const int bh = blockIdx.y, b = bh >> 3, h = bh & 7, hb = h * 64;
  const int tid = threadIdx.x, wid = tid >> 6, lane = tid & 63;
  const int l15 = lane & 15, hq = lane >> 4;
  const int q0 = blockIdx.x * 128 + wid * 32;
  const long rb = (long)b * SEQ_L;

  bf16x8 qf[2][2];
#pragma unroll
  for (int ks = 0; ks < 2; ++ks)
#pragma unroll
    for (int c2 = 0; c2 < 2; ++c2)
      qf[ks][c2] = ldb8(Q + (rb + q0 + c2 * 16 + l15) * D_MODEL + hb + ks * 32 + 8 * hq);

  f32x4 o_l[4][2], o_g[4][2];
#pragma unroll
  for (int dt = 0; dt < 4; ++dt)
#pragma unroll
    for (int c2 = 0; c2 < 2; ++c2){
      o_l[dt][c2] = f32x4{0.f, 0.f, 0.f, 0.f};
      o_g[dt][c2] = f32x4{0.f, 0.f, 0.f, 0.f};
    }
  float m_l[2] = {-1e30f, -1e30f}, s_l[2] = {0.f, 0.f};
  float m_g[2] = {-1e30f, -1e30f}, s_g[2] = {0.f, 0.f};

  const int slo = l15 + 16 * ((hq & 1) * 2);
  const int shi = slo + 16;
  const bool sel = hq >= 2;

  for (int kv = 0; kv < SEQ_L; kv += 64){
    bf16x8 vf[4][2];
#pragma unroll
    for (int dt = 0; dt < 4; ++dt)
#pragma unroll
      for (int c = 0; c < 2; ++c)
        vf[dt][c] = ldb8(Vt + ((long)b * D_MODEL + hb + dt * 16 + l15) * SEQ_L + kv + c * 32 + 8 * hq);

    auto process_path = [&](const unsigned short* __restrict__ Kp,
                            float (&mrun)[2], float (&srun)[2], f32x4 (&oacc)[4][2]){
      f32x4 s[4][2];
#pragma unroll
      for (int t = 0; t < 4; ++t){ s[t][0] = f32x4{0.f,0.f,0.f,0.f}; s[t][1] = f32x4{0.f,0.f,0.f,0.f}; }
#pragma unroll
      for (int ks = 0; ks < 2; ++ks){
#pragma unroll
        for (int t = 0; t < 4; ++t){
          bf16x8 kf = ldb8(Kp + (rb + kv + t * 16 + l15) * D_MODEL + hb + ks * 32 + 8 * hq);
          s[t][0] = mfma16(kf, qf[ks][0], s[t][0]);
          s[t][1] = mfma16(kf, qf[ks][1], s[t][1]);
        }
      }
#pragma unroll
      for (int c2 = 0; c2 < 2; ++c2){
        float mx = -1e30f;
#pragma unroll
        for (int t = 0; t < 4; ++t)
#pragma unroll
          for (int r = 0; r < 4; ++r) mx = fmaxf(mx, s[t][c2][r]);
        mx = fmaxf(mx, __shfl_xor(mx, 16));
        mx = fmaxf(mx, __shfl_xor(mx, 32));
        float mn = fmaxf(mrun[c2], mx);
        float resc = exp2f((mrun[c2] - mn) * LOG2E_F);
        float sum = 0.f;
#pragma unroll
        for (int t = 0; t < 4; ++t)
#pragma unroll
          for (int r = 0; r < 4; ++r){
            float p = exp2f((s[t][c2][r] - mn) * LOG2E_F);
            s[t][c2][r] = p; sum += p;
          }
        sum += __shfl_xor(sum, 16);
        sum += __shfl_xor(sum, 32);
        srun[c2] = srun[c2] * resc + sum;
        mrun[c2] = mn;
#pragma unroll
        for (int dt = 0; dt < 4; ++dt) oacc[dt][c2] = oacc[dt][c2] * resc;
        unsigned pk[4][2];
#pragma unroll
        for (int t = 0; t < 4; ++t){
          pk[t][0] = pack2bf(s[t][c2][0], s[t][c2][1]);
          pk[t][1] = pack2bf(s[t][c2][2], s[t][c2][3]);
        }
        unsigned lo[4][2], hi[4][2];
#pragma unroll
        for (int t = 0; t < 4; ++t)
#pragma unroll
          for (int j = 0; j < 2; ++j){
            lo[t][j] = (unsigned)__shfl((int)pk[t][j], slo, 64);
            hi[t][j] = (unsigned)__shfl((int)pk[t][j], shi, 64);
          }
#pragma unroll
        for (int c = 0; c < 2; ++c){
          const int t0 = 2 * c, t1 = 2 * c + 1;
          unsigned u0 = sel ? lo[t1][0] : lo[t0][0];
          unsigned u1 = sel ? lo[t1][1] : lo[t0][1];
          unsigned u2 = sel ? hi[t1][0] : hi[t0][0];
          unsigned u3 = sel ? hi[t1][1] : hi[t0][1];
          union { bf16x8 v; unsigned u[4]; } pb;
          pb.u[0] = u0; pb.u[1] = u1; pb.u[2] = u2; pb.u[3] = u3;
#pragma unroll
          for (int dt = 0; dt < 4; ++dt) oacc[dt][c2] = mfma16(vf[dt][c], pb.v, oacc[dt][c2]);
        }
      }
    };
    process_path(KLp, m_l, s_l, o_l);
    process_path(KGp, m_g, s_g, o_g);
  }

#pragma unroll
  for (int c2 = 0; c2 < 2; ++c2){
    float il = 1.f / s_l[c2], ig = 1.f / s_g[c2];
#pragma unroll
    for (int dt = 0; dt < 4; ++dt){
      float v0 = o_l[dt][c2][0] * il + o_g[dt][c2][0] * ig;
      float v1 = o_l[dt][c2][1] * il + o_g[dt][c2][1] * ig;
      float v2 = o_l[dt][c2][2] * il + o_g[dt][c2][2] * ig;
      float v3 = o_l[dt][c2][3] * il + o_g[dt][c2][3] * ig;
      uint2 pk2; pk2.x = pack2bf(v0, v1); pk2.y = pack2bf(v2, v3);
      *reinterpret_cast<uint2*>(X + (rb + q0 + c2 * 16 + l15) * D_MODEL + hb + dt * 16 + 4 * hq) = pk2;
    }
  }
}

// ---------------- host ----------------
extern "C" void kernel_launch(void* const* d_in, const int* in_sizes, int n_in,
                              void* d_out, int out_size, void* d_ws, size_t ws_size,
                              hipStream_t stream)
{
  const float* query = (const float*)d_in[0];
  const float* key   = (const float*)d_in[1];
  const float* value = (const float*)d_in[2];
  const float* w3    = (const float*)d_in[3];
  const float* cb3   = (const float*)d_in[4];
  const float* w5    = (const float*)d_in[5];
  const float* cb5   = (const float*)d_in[6];
  const float* gamma = (const float*)d_in[7];
  const float* beta  = (const float*)d_in[8];
  const float* mean  = (const float*)d_in[9];
  const float* var   = (const float*)d_in[10];
  const float* wq    = (const float*)d_in[11];
  const float* bq    = (const float*)d_in[12];
  const float* wkl   = (const float*)d_in[13];
  const float* bkl   = (const float*)d_in[14];
  const float* wkg   = (const float*)d_in[15];
  const float* bkg   = (const float*)d_in[16];
  const float* wv    = (const float*)d_in[17];
  const float* bv    = (const float*)d_in[18];
  const float* wo    = (const float*)d_in[19];
  const float* bo    = (const float*)d_in[20];

  char* ws = (char*)d_ws;
  const size_t MB = 1024 * 1024;
  unsigned short* qb   = (unsigned short*)(ws + 0 * MB);
  unsigned short* kb   = (unsigned short*)(ws + 8 * MB);
  unsigned short* vb   = (unsigned short*)(ws + 16 * MB);
  unsigned short* Qm   = (unsigned short*)(ws + 24 * MB);
  unsigned short* KLm  = (unsigned short*)(ws + 32 * MB);
  unsigned short* KGm  = (unsigned short*)(ws + 40 * MB);
  unsigned short* Vm   = qb;   // reuse: query-bf16 dead after Q GEMM
  unsigned short* Vt   = (unsigned short*)(ws + 48 * MB);
  unsigned short* Xm   = vb;   // reuse: value-bf16 dead after V GEMM
  unsigned short* wqb  = (unsigned short*)(ws + 56 * MB);
  unsigned short* wkgb = (unsigned short*)(ws + 56 * MB + 512 * 1024);
  unsigned short* wvb  = (unsigned short*)(ws + 57 * MB);
  unsigned short* wob  = (unsigned short*)(ws + 57 * MB + 512 * 1024);
  unsigned short* Acat = (unsigned short*)(ws + 58 * MB);
  unsigned short* Bcat = (unsigned short*)(ws + 59 * MB);
  unsigned short* Weff = (unsigned short*)(ws + 64 * MB);
  float*          beff = (float*)(ws + 67 * MB);
  unsigned short* zeros= (unsigned short*)(ws + 67 * MB + 4096);

  hipMemsetAsync(zeros, 0, 256, stream);

  const int NQKV = BLROWS * D_MODEL;      // 4,194,304
  const int NW   = D_MODEL * D_MODEL;     // 262,144
  dim3 tb(256);
  k_cast<<<NQKV / 1024, tb, 0, stream>>>(query, qb, NQKV, 1.f);
  k_cast<<<NQKV / 1024, tb, 0, stream>>>(key,   kb, NQKV, 1.f);
  k_cast<<<NQKV / 1024, tb, 0, stream>>>(value, vb, NQKV, 1.f);
  k_cast<<<NW / 1024, tb, 0, stream>>>(wq,  wqb,  NW, 0.125f);   // fold 1/sqrt(dk)
  k_cast<<<NW / 1024, tb, 0, stream>>>(wkg, wkgb, NW, 1.f);
  k_cast<<<NW / 1024, tb, 0, stream>>>(wv,  wvb,  NW, 1.f);
  k_cast<<<NW / 1024, tb, 0, stream>>>(wo,  wob,  NW, 1.f);
  k_acat<<<(512 * 1024) / 256, tb, 0, stream>>>(wkl, gamma, var, Acat);
  k_bcat<<<(5 * 512 * 1024) / 256, tb, 0, stream>>>(w3, w5, Bcat);
  k_beff<<<2, tb, 0, stream>>>(wkl, gamma, beta, mean, var, cb3, cb5, bkl, beff);

  // Weff[t] = Acat @ Bcat[t]^T   (M=512, N=512, K=1024), z = t
  k_gemm<0><<<dim3(4, 4, 5), tb, 0, stream>>>(Acat, Bcat, Weff, nullptr, 0.f,
      512, 512, 1024, 1024, 1024, 512, 524288L, 262144L, nullptr);

  // projections
  k_gemm<0><<<dim3(64, 4), tb, 0, stream>>>(qb, wqb, Qm, bq, 0.125f,
      BLROWS, D_MODEL, D_MODEL, D_MODEL, D_MODEL, D_MODEL, 0L, 0L, nullptr);
  k_gemm<2><<<dim3(64, 4), tb, 0, stream>>>(kb, Weff, KLm, beff, 1.f,
      BLROWS, D_MODEL, 2560, D_MODEL, D_MODEL, D_MODEL, 0L, 0L, zeros);
  k_gemm<0><<<dim3(64, 4), tb, 0, stream>>>(kb, wkgb, KGm, bkg, 1.f,
      BLROWS, D_MODEL, D_MODEL, D_MODEL, D_MODEL, D_MODEL, 0L, 0L, nullptr);
  k_gemm<0><<<dim3(64, 4), tb, 0, stream>>>(vb, wvb, Vm, bv, 1.f,
      BLROWS, D_MODEL, D_MODEL, D_MODEL, D_MODEL, D_MODEL, 0L, 0L, nullptr);

  k_transpose<<<dim3(32, 8, 4), tb, 0, stream>>>(Vm, Vt);
  k_attn<<<dim3(16, 32), tb, 0, stream>>>(Qm, KLm, KGm, Vt, Xm);

  k_gemm<1><<<dim3(64, 4), tb, 0, stream>>>(Xm, wob, d_out, bo, 1.f,
      BLROWS, D_MODEL, D_MODEL, D_MODEL, D_MODEL, D_MODEL, 0L, 0L, nullptr);
}

// Round 3
// 443.825 us; speedup vs baseline: 1.1635x; 1.1635x over previous
//
#include <hip/hip_runtime.h>
#include <hip/hip_bf16.h>

#define D_MODEL 512
#define SEQ_L   2048
#define NBATCH  4
#define BLROWS  8192
#define BN_EPS_F 1e-5f
#define QK_SCALE 0.18033688011112042f  /* (1/sqrt(64)) * log2(e) */

typedef __attribute__((ext_vector_type(8))) short bf16x8;
typedef __attribute__((ext_vector_type(4))) float f32x4;
typedef __attribute__((ext_vector_type(16))) float f32x16;
typedef __attribute__((ext_vector_type(2))) int i32x2;

__device__ __forceinline__ unsigned short f2bf(float f){
  union { float f; unsigned u; } x; x.f = f;
  return (unsigned short)((x.u + 0x7fffu + ((x.u >> 16) & 1u)) >> 16);
}
__device__ __forceinline__ unsigned pack2bf(float a, float b){
  return (unsigned)f2bf(a) | ((unsigned)f2bf(b) << 16);
}
__device__ __forceinline__ unsigned cvt_pk(float a, float b){
  unsigned r;
  asm("v_cvt_pk_bf16_f32 %0, %1, %2" : "=v"(r) : "v"(a), "v"(b));
  return r;
}
__device__ __forceinline__ f32x4 mfma16(bf16x8 a, bf16x8 b, f32x4 c){
  return __builtin_amdgcn_mfma_f32_16x16x32_bf16(a, b, c, 0, 0, 0);
}
__device__ __forceinline__ f32x16 mfma32(bf16x8 a, bf16x8 b, f32x16 c){
  return __builtin_amdgcn_mfma_f32_32x32x16_bf16(a, b, c, 0, 0, 0);
}
__device__ __forceinline__ bf16x8 ldb8(const unsigned short* p){
  return *reinterpret_cast<const bf16x8*>(p);
}

// ---------------- elementwise prep ----------------
__global__ void k_cast(const float* __restrict__ src, unsigned short* __restrict__ dst,
                       int n, float scale){
  int i = (blockIdx.x * blockDim.x + threadIdx.x) * 4;
  if (i >= n) return;
  float4 v = *reinterpret_cast<const float4*>(src + i);
  uint2 o;
  o.x = pack2bf(v.x * scale, v.y * scale);
  o.y = pack2bf(v.z * scale, v.w * scale);
  *reinterpret_cast<uint2*>(dst + i) = o;
}

__global__ void k_acat(const float* __restrict__ wkl, const float* __restrict__ gamma,
                       const float* __restrict__ var, unsigned short* __restrict__ Acat){
  int idx = blockIdx.x * blockDim.x + threadIdx.x;
  int o = idx >> 10, ch = idx & 1023;
  int c = (ch < 512) ? (512 + ch) : (ch - 512);
  float a = gamma[c] * rsqrtf(var[c] + BN_EPS_F);
  Acat[idx] = f2bf(wkl[o * 1024 + c] * a);
}

__global__ void k_bcat(const float* __restrict__ w3, const float* __restrict__ w5,
                       unsigned short* __restrict__ Bcat){
  int idx = blockIdx.x * blockDim.x + threadIdx.x;
  int t = idx >> 19; int r = idx & 524287;
  int ci = r >> 10, ch = r & 1023;
  float v;
  if (ch < 512) v = w5[ch * 2560 + ci * 5 + t];
  else {
    int c3 = ch - 512;
    v = (t >= 1 && t <= 3) ? w3[c3 * 1536 + ci * 3 + (t - 1)] : 0.0f;
  }
  Bcat[idx] = f2bf(v);
}

__global__ void k_beff(const float* __restrict__ wkl, const float* __restrict__ gamma,
                       const float* __restrict__ beta, const float* __restrict__ mean,
                       const float* __restrict__ var, const float* __restrict__ cb3,
                       const float* __restrict__ cb5, const float* __restrict__ bkl,
                       float* __restrict__ beff){
  int o = blockIdx.x * blockDim.x + threadIdx.x;
  if (o >= 512) return;
  float acc = bkl[o];
  for (int c = 0; c < 1024; ++c){
    float a = gamma[c] * rsqrtf(var[c] + BN_EPS_F);
    float cb = (c < 512) ? cb3[c] : cb5[c - 512];
    acc += wkl[o * 1024 + c] * (a * cb + beta[c] - a * mean[c]);
  }
  beff[o] = acc;
}

// ---------------- GEMM (unchanged, proven) ----------------
template<int MODE>
__global__ __launch_bounds__(256, 2) void k_gemm(
    const unsigned short* __restrict__ A, const unsigned short* __restrict__ Bm,
    void* __restrict__ Cp, const float* __restrict__ bias, float bias_scale,
    int M, int N, int K, int lda, int ldb, int ldc,
    long sBz, long sCz, const unsigned short* __restrict__ zeros)
{
  __shared__ unsigned short As[128 * 64];
  __shared__ unsigned short Bs[128 * 64];
  const int m0 = blockIdx.x * 128, n0 = blockIdx.y * 128;
  const unsigned short* Bz = Bm + (long)blockIdx.z * sBz;
  const int tid = threadIdx.x, wid = tid >> 6, lane = tid & 63;
  const int l15 = lane & 15, hq = lane >> 4;
  const int wr = wid >> 1, wc = wid & 1;
  f32x4 acc[4][4];
#pragma unroll
  for (int m = 0; m < 4; ++m)
#pragma unroll
    for (int n = 0; n < 4; ++n) acc[m][n] = f32x4{0.f, 0.f, 0.f, 0.f};
  const int nkt = K >> 6;
  const int soff = tid * 8;
  const int srow = tid >> 3;
  const int scol = (tid & 7) * 8;
  for (int kt = 0; kt < nkt; ++kt){
    __syncthreads();
    bf16x8 va[4], vb[4];
    if (MODE == 2){
      const int t = kt >> 3; const int ci0 = (kt & 7) << 6;
#pragma unroll
      for (int i = 0; i < 4; ++i){
        int row = srow + i * 32;
        int gr = m0 + row;
        int sl = (gr & (SEQ_L - 1)) + t - 2;
        const unsigned short* sp = ((unsigned)sl < (unsigned)SEQ_L)
            ? (A + (long)(gr + t - 2) * lda + ci0 + scol) : zeros;
        va[i] = ldb8(sp);
        vb[i] = ldb8(Bz + (long)t * 262144 + (long)(n0 + row) * ldb + ci0 + scol);
      }
    } else {
      const int k0 = kt << 6;
#pragma unroll
      for (int i = 0; i < 4; ++i){
        int row = srow + i * 32;
        va[i] = ldb8(A + (long)(m0 + row) * lda + k0 + scol);
        vb[i] = ldb8(Bz + (long)(n0 + row) * ldb + k0 + scol);
      }
    }
#pragma unroll
    for (int i = 0; i < 4; ++i){
      *reinterpret_cast<bf16x8*>(As + soff + i * 2048) = va[i];
      *reinterpret_cast<bf16x8*>(Bs + soff + i * 2048) = vb[i];
    }
    __syncthreads();
#pragma unroll
    for (int ks = 0; ks < 2; ++ks){
      const int kb = ks * 32 + 8 * hq;
      bf16x8 af[4], bfr[4];
#pragma unroll
      for (int m = 0; m < 4; ++m) af[m] = ldb8(As + (wr * 64 + m * 16 + l15) * 64 + kb);
#pragma unroll
      for (int n = 0; n < 4; ++n) bfr[n] = ldb8(Bs + (wc * 64 + n * 16 + l15) * 64 + kb);
#pragma unroll
      for (int m = 0; m < 4; ++m)
#pragma unroll
        for (int n = 0; n < 4; ++n) acc[m][n] = mfma16(af[m], bfr[n], acc[m][n]);
    }
  }
  const int crow0 = m0 + wr * 64, ccol0 = n0 + wc * 64;
#pragma unroll
  for (int n = 0; n < 4; ++n){
    int col = ccol0 + n * 16 + l15;
    float bv = bias ? bias[col] * bias_scale : 0.f;
#pragma unroll
    for (int m = 0; m < 4; ++m){
      int rowb = crow0 + m * 16 + 4 * hq;
#pragma unroll
      for (int r = 0; r < 4; ++r){
        float v = acc[m][n][r] + bv;
        long off = (long)(rowb + r) * ldc + col + (long)blockIdx.z * sCz;
        if (MODE == 1) ((float*)Cp)[off] = v;
        else ((unsigned short*)Cp)[off] = f2bf(v);
      }
    }
  }
}

// ---------------- V transpose ----------------
__global__ __launch_bounds__(256) void k_transpose(const unsigned short* __restrict__ V,
                                                   unsigned short* __restrict__ Vt){
  __shared__ unsigned short t_lds[64][72];
  const int l0 = blockIdx.x * 64, d0 = blockIdx.y * 64, b = blockIdx.z;
  const int tid = threadIdx.x;
  const int rr = tid >> 3, cc = (tid & 7) * 8;
#pragma unroll
  for (int p = 0; p < 2; ++p){
    int r = rr + p * 32;
    bf16x8 v = ldb8(V + ((long)(b * SEQ_L + l0 + r)) * D_MODEL + d0 + cc);
#pragma unroll
    for (int j = 0; j < 8; ++j) t_lds[r][cc + j] = (unsigned short)v[j];
  }
  __syncthreads();
#pragma unroll
  for (int p = 0; p < 2; ++p){
    int dr = rr + p * 32;
    bf16x8 o;
#pragma unroll
    for (int j = 0; j < 8; ++j) o[j] = (short)t_lds[cc + j][dr];
    *reinterpret_cast<bf16x8*>(Vt + ((long)(b * D_MODEL + d0 + dr)) * SEQ_L + l0 + cc) = o;
  }
}

// ---------------- flash attention: 32x32 swapped-QK^T, in-register softmax ----------------
// Per wave: 32 q-rows. mfma32(K,Q) -> lane(q=lane&31,hi=lane>>5) holds S^T rows
// k_local = (reg&3)+8*(reg>>2)+4*hi. Row reduce = in-reg + 1 permlane32_swap.
// P repack derivation (verified): u[t][r4][w] = P pair at k=8*r4+4*hi+2w+{0,1}.
// B-frag chunk kc (t=kc>>1,kk=kc&1) word w0..w3 = k 16kk+8hi+{0,1},{2,3},{4,5},{6,7}:
//   rA = swap(u[t][2kk][0], u[t][2kk+1][0]) -> rA[0]={lo:own lo-group, hi:partner}=w0,
//                                              rA[1]={lo:partner, hi:own}=w2.
__global__ __launch_bounds__(256, 2) void k_attn(
    const unsigned short* __restrict__ Q, const unsigned short* __restrict__ KLp,
    const unsigned short* __restrict__ KGp, const unsigned short* __restrict__ Vt,
    unsigned short* __restrict__ X)
{
  const int lin = blockIdx.x + (blockIdx.y << 4);
  const int sw  = ((lin & 7) << 6) + (lin >> 3);
  const int qi = sw & 15, bh = sw >> 4;
  const int b = bh >> 3, hb = (bh & 7) << 6;
  const int tid = threadIdx.x, wid = tid >> 6, lane = tid & 63;
  const int l31 = lane & 31, hi = lane >> 5;
  const int q0 = qi * 128 + wid * 32;
  const long rb = (long)b * SEQ_L;

  const long qrow = (rb + q0 + l31) * D_MODEL + hb + hi * 8;
  bf16x8 qf[4];
#pragma unroll
  for (int ch = 0; ch < 4; ++ch) qf[ch] = ldb8(Q + qrow + ch * 16);

  f32x16 o_l[2], o_g[2];
#pragma unroll
  for (int dt = 0; dt < 2; ++dt){ o_l[dt] = 0.f; o_g[dt] = 0.f; }
  float m_l = -1e30f, s_l = 0.f, m_g = -1e30f, s_g = 0.f;

  const long vbase = ((long)(b * D_MODEL + hb + l31)) * SEQ_L + hi * 8;
  const long kbase0 = (rb + l31) * D_MODEL + hb + hi * 8;

  for (int kv = 0; kv < SEQ_L; kv += 64){
    bf16x8 vf[2][4];
#pragma unroll
    for (int dt = 0; dt < 2; ++dt)
#pragma unroll
      for (int kc = 0; kc < 4; ++kc)
        vf[dt][kc] = ldb8(Vt + vbase + (long)dt * 32 * SEQ_L + kv + kc * 16);

    auto path = [&](const unsigned short* __restrict__ Kp,
                    float& mrun, float& srun, f32x16* o){
      const long kb0 = kbase0 + (long)kv * D_MODEL;
      f32x16 sa = 0.f, sb = 0.f;
#pragma unroll
      for (int ch = 0; ch < 4; ++ch){
        bf16x8 k0 = ldb8(Kp + kb0 + ch * 16);
        bf16x8 k1 = ldb8(Kp + kb0 + 32 * D_MODEL + ch * 16);
        sa = mfma32(k0, qf[ch], sa);
        sb = mfma32(k1, qf[ch], sb);
      }
      float pm = sa[0];
#pragma unroll
      for (int r = 1; r < 16; ++r) pm = fmaxf(pm, sa[r]);
#pragma unroll
      for (int r = 0; r < 16; ++r) pm = fmaxf(pm, sb[r]);
      i32x2 pr = __builtin_amdgcn_permlane32_swap(__float_as_int(pm), __float_as_int(pm), false, false);
      pm = fmaxf(pm, fmaxf(__int_as_float(pr[0]), __int_as_float(pr[1])));
      if (__any(pm > mrun + 11.0f)){
        float mn = fmaxf(mrun, pm);
        float rs = exp2f(mrun - mn);
        srun *= rs; mrun = mn;
#pragma unroll
        for (int r = 0; r < 16; ++r){ o[0][r] *= rs; o[1][r] *= rs; }
      }
      float sum = 0.f;
#pragma unroll
      for (int r = 0; r < 16; ++r){ sa[r] = exp2f(sa[r] - mrun); sum += sa[r]; }
#pragma unroll
      for (int r = 0; r < 16; ++r){ sb[r] = exp2f(sb[r] - mrun); sum += sb[r]; }
      i32x2 sr = __builtin_amdgcn_permlane32_swap(__float_as_int(sum), __float_as_int(sum), false, false);
      srun += __int_as_float(sr[0]) + __int_as_float(sr[1]);
      unsigned u[2][4][2];
#pragma unroll
      for (int r4 = 0; r4 < 4; ++r4){
        u[0][r4][0] = cvt_pk(sa[r4 * 4 + 0], sa[r4 * 4 + 1]);
        u[0][r4][1] = cvt_pk(sa[r4 * 4 + 2], sa[r4 * 4 + 3]);
        u[1][r4][0] = cvt_pk(sb[r4 * 4 + 0], sb[r4 * 4 + 1]);
        u[1][r4][1] = cvt_pk(sb[r4 * 4 + 2], sb[r4 * 4 + 3]);
      }
#pragma unroll
      for (int kc = 0; kc < 4; ++kc){
        const int t = kc >> 1, kk = kc & 1;
        i32x2 rA = __builtin_amdgcn_permlane32_swap((int)u[t][2 * kk][0], (int)u[t][2 * kk + 1][0], false, false);
        i32x2 rB = __builtin_amdgcn_permlane32_swap((int)u[t][2 * kk][1], (int)u[t][2 * kk + 1][1], false, false);
        union { bf16x8 v; int w[4]; } pb;
        pb.w[0] = rA[0]; pb.w[1] = rB[0]; pb.w[2] = rA[1]; pb.w[3] = rB[1];
        o[0] = mfma32(vf[0][kc], pb.v, o[0]);
        o[1] = mfma32(vf[1][kc], pb.v, o[1]);
      }
    };
    path(KLp, m_l, s_l, o_l);
    path(KGp, m_g, s_g, o_g);
  }

  const float il = 1.f / s_l, ig = 1.f / s_g;
  const long xrow = (rb + q0 + l31) * D_MODEL + hb + hi * 4;
#pragma unroll
  for (int dt = 0; dt < 2; ++dt)
#pragma unroll
    for (int r4 = 0; r4 < 4; ++r4){
      float v0 = o_l[dt][r4 * 4 + 0] * il + o_g[dt][r4 * 4 + 0] * ig;
      float v1 = o_l[dt][r4 * 4 + 1] * il + o_g[dt][r4 * 4 + 1] * ig;
      float v2 = o_l[dt][r4 * 4 + 2] * il + o_g[dt][r4 * 4 + 2] * ig;
      float v3 = o_l[dt][r4 * 4 + 3] * il + o_g[dt][r4 * 4 + 3] * ig;
      uint2 pk2; pk2.x = cvt_pk(v0, v1); pk2.y = cvt_pk(v2, v3);
      *reinterpret_cast<uint2*>(X + xrow + dt * 32 + r4 * 8) = pk2;
    }
}

// ---------------- host ----------------
extern "C" void kernel_launch(void* const* d_in, const int* in_sizes, int n_in,
                              void* d_out, int out_size, void* d_ws, size_t ws_size,
                              hipStream_t stream)
{
  const float* query = (const float*)d_in[0];
  const float* key   = (const float*)d_in[1];
  const float* value = (const float*)d_in[2];
  const float* w3    = (const float*)d_in[3];
  const float* cb3   = (const float*)d_in[4];
  const float* w5    = (const float*)d_in[5];
  const float* cb5   = (const float*)d_in[6];
  const float* gamma = (const float*)d_in[7];
  const float* beta  = (const float*)d_in[8];
  const float* mean  = (const float*)d_in[9];
  const float* var   = (const float*)d_in[10];
  const float* wq    = (const float*)d_in[11];
  const float* bq    = (const float*)d_in[12];
  const float* wkl   = (const float*)d_in[13];
  const float* bkl   = (const float*)d_in[14];
  const float* wkg   = (const float*)d_in[15];
  const float* bkg   = (const float*)d_in[16];
  const float* wv    = (const float*)d_in[17];
  const float* bv    = (const float*)d_in[18];
  const float* wo    = (const float*)d_in[19];
  const float* bo    = (const float*)d_in[20];

  char* ws = (char*)d_ws;
  const size_t MB = 1024 * 1024;
  unsigned short* qb   = (unsigned short*)(ws + 0 * MB);
  unsigned short* kb   = (unsigned short*)(ws + 8 * MB);
  unsigned short* vb   = (unsigned short*)(ws + 16 * MB);
  unsigned short* Qm   = (unsigned short*)(ws + 24 * MB);
  unsigned short* KLm  = (unsigned short*)(ws + 32 * MB);
  unsigned short* KGm  = (unsigned short*)(ws + 40 * MB);
  unsigned short* Vm   = qb;   // reuse
  unsigned short* Vt   = (unsigned short*)(ws + 48 * MB);
  unsigned short* Xm   = vb;   // reuse
  unsigned short* wqb  = (unsigned short*)(ws + 56 * MB);
  unsigned short* wkgb = (unsigned short*)(ws + 56 * MB + 512 * 1024);
  unsigned short* wvb  = (unsigned short*)(ws + 57 * MB);
  unsigned short* wob  = (unsigned short*)(ws + 57 * MB + 512 * 1024);
  unsigned short* Acat = (unsigned short*)(ws + 58 * MB);
  unsigned short* Bcat = (unsigned short*)(ws + 59 * MB);
  unsigned short* Weff = (unsigned short*)(ws + 64 * MB);
  float*          beff = (float*)(ws + 67 * MB);
  unsigned short* zeros= (unsigned short*)(ws + 67 * MB + 4096);

  hipMemsetAsync(zeros, 0, 256, stream);

  const int NQKV = BLROWS * D_MODEL;
  const int NW   = D_MODEL * D_MODEL;
  dim3 tb(256);
  k_cast<<<NQKV / 1024, tb, 0, stream>>>(query, qb, NQKV, 1.f);
  k_cast<<<NQKV / 1024, tb, 0, stream>>>(key,   kb, NQKV, 1.f);
  k_cast<<<NQKV / 1024, tb, 0, stream>>>(value, vb, NQKV, 1.f);
  k_cast<<<NW / 1024, tb, 0, stream>>>(wq,  wqb,  NW, QK_SCALE);
  k_cast<<<NW / 1024, tb, 0, stream>>>(wkg, wkgb, NW, 1.f);
  k_cast<<<NW / 1024, tb, 0, stream>>>(wv,  wvb,  NW, 1.f);
  k_cast<<<NW / 1024, tb, 0, stream>>>(wo,  wob,  NW, 1.f);
  k_acat<<<(512 * 1024) / 256, tb, 0, stream>>>(wkl, gamma, var, Acat);
  k_bcat<<<(5 * 512 * 1024) / 256, tb, 0, stream>>>(w3, w5, Bcat);
  k_beff<<<2, tb, 0, stream>>>(wkl, gamma, beta, mean, var, cb3, cb5, bkl, beff);

  k_gemm<0><<<dim3(4, 4, 5), tb, 0, stream>>>(Acat, Bcat, Weff, nullptr, 0.f,
      512, 512, 1024, 1024, 1024, 512, 524288L, 262144L, nullptr);

  k_gemm<0><<<dim3(64, 4), tb, 0, stream>>>(qb, wqb, Qm, bq, QK_SCALE,
      BLROWS, D_MODEL, D_MODEL, D_MODEL, D_MODEL, D_MODEL, 0L, 0L, nullptr);
  k_gemm<2><<<dim3(64, 4), tb, 0, stream>>>(kb, Weff, KLm, beff, 1.f,
      BLROWS, D_MODEL, 2560, D_MODEL, D_MODEL, D_MODEL, 0L, 0L, zeros);
  k_gemm<0><<<dim3(64, 4), tb, 0, stream>>>(kb, wkgb, KGm, bkg, 1.f,
      BLROWS, D_MODEL, D_MODEL, D_MODEL, D_MODEL, D_MODEL, 0L, 0L, nullptr);
  k_gemm<0><<<dim3(64, 4), tb, 0, stream>>>(vb, wvb, Vm, bv, 1.f,
      BLROWS, D_MODEL, D_MODEL, D_MODEL, D_MODEL, D_MODEL, 0L, 0L, nullptr);

  k_transpose<<<dim3(32, 8, 4), tb, 0, stream>>>(Vm, Vt);
  k_attn<<<dim3(16, 32), tb, 0, stream>>>(Qm, KLm, KGm, Vt, Xm);

  k_gemm<1><<<dim3(64, 4), tb, 0, stream>>>(Xm, wob, d_out, bo, 1.f,
      BLROWS, D_MODEL, D_MODEL, D_MODEL, D_MODEL, D_MODEL, 0L, 0L, nullptr);
}

// Round 4
// 441.055 us; speedup vs baseline: 1.1708x; 1.0063x over previous
//
#include <hip/hip_runtime.h>
#include <hip/hip_bf16.h>

#define D_MODEL 512
#define SEQ_L   2048
#define NBATCH  4
#define BLROWS  8192
#define BN_EPS_F 1e-5f
#define QK_SCALE 0.18033688011112042f  /* (1/sqrt(64)) * log2(e) */

typedef __attribute__((ext_vector_type(8))) short bf16x8;
typedef __attribute__((ext_vector_type(4))) float f32x4;
typedef __attribute__((ext_vector_type(16))) float f32x16;
typedef __attribute__((ext_vector_type(2))) int i32x2;

__device__ __forceinline__ unsigned short f2bf(float f){
  union { float f; unsigned u; } x; x.f = f;
  return (unsigned short)((x.u + 0x7fffu + ((x.u >> 16) & 1u)) >> 16);
}
__device__ __forceinline__ unsigned pack2bf(float a, float b){
  return (unsigned)f2bf(a) | ((unsigned)f2bf(b) << 16);
}
__device__ __forceinline__ unsigned cvt_pk(float a, float b){
  unsigned r;
  asm("v_cvt_pk_bf16_f32 %0, %1, %2" : "=v"(r) : "v"(a), "v"(b));
  return r;
}
__device__ __forceinline__ f32x4 mfma16(bf16x8 a, bf16x8 b, f32x4 c){
  return __builtin_amdgcn_mfma_f32_16x16x32_bf16(a, b, c, 0, 0, 0);
}
__device__ __forceinline__ f32x16 mfma32(bf16x8 a, bf16x8 b, f32x16 c){
  return __builtin_amdgcn_mfma_f32_32x32x16_bf16(a, b, c, 0, 0, 0);
}
__device__ __forceinline__ bf16x8 ldb8(const unsigned short* p){
  return *reinterpret_cast<const bf16x8*>(p);
}
// async global->LDS, 16B per lane; LDS dest = wave-uniform base + lane*16
__device__ __forceinline__ void gld16(const void* g, void* l){
  __builtin_amdgcn_global_load_lds(
      (const __attribute__((address_space(1))) unsigned*)g,
      (__attribute__((address_space(3))) unsigned*)l, 16, 0, 0);
}

// ---------------- elementwise prep ----------------
__global__ void k_cast(const float* __restrict__ src, unsigned short* __restrict__ dst,
                       int n, float scale){
  int i = (blockIdx.x * blockDim.x + threadIdx.x) * 4;
  if (i >= n) return;
  float4 v = *reinterpret_cast<const float4*>(src + i);
  uint2 o;
  o.x = pack2bf(v.x * scale, v.y * scale);
  o.y = pack2bf(v.z * scale, v.w * scale);
  *reinterpret_cast<uint2*>(dst + i) = o;
}

__global__ void k_acat(const float* __restrict__ wkl, const float* __restrict__ gamma,
                       const float* __restrict__ var, unsigned short* __restrict__ Acat){
  int idx = blockIdx.x * blockDim.x + threadIdx.x;
  int o = idx >> 10, ch = idx & 1023;
  int c = (ch < 512) ? (512 + ch) : (ch - 512);
  float a = gamma[c] * rsqrtf(var[c] + BN_EPS_F);
  Acat[idx] = f2bf(wkl[o * 1024 + c] * a);
}

__global__ void k_bcat(const float* __restrict__ w3, const float* __restrict__ w5,
                       unsigned short* __restrict__ Bcat){
  int idx = blockIdx.x * blockDim.x + threadIdx.x;
  int t = idx >> 19; int r = idx & 524287;
  int ci = r >> 10, ch = r & 1023;
  float v;
  if (ch < 512) v = w5[ch * 2560 + ci * 5 + t];
  else {
    int c3 = ch - 512;
    v = (t >= 1 && t <= 3) ? w3[c3 * 1536 + ci * 3 + (t - 1)] : 0.0f;
  }
  Bcat[idx] = f2bf(v);
}

__global__ void k_beff(const float* __restrict__ wkl, const float* __restrict__ gamma,
                       const float* __restrict__ beta, const float* __restrict__ mean,
                       const float* __restrict__ var, const float* __restrict__ cb3,
                       const float* __restrict__ cb5, const float* __restrict__ bkl,
                       float* __restrict__ beff){
  int o = blockIdx.x * blockDim.x + threadIdx.x;
  if (o >= 512) return;
  float acc = bkl[o];
  for (int c = 0; c < 1024; ++c){
    float a = gamma[c] * rsqrtf(var[c] + BN_EPS_F);
    float cb = (c < 512) ? cb3[c] : cb5[c - 512];
    acc += wkl[o * 1024 + c] * (a * cb + beta[c] - a * mean[c]);
  }
  beff[o] = acc;
}

// ---------------- GEMM with global_load_lds staging ----------------
// C[m,n] = sum_k A[m,k]*B[n,k] (+bias[n]); MODE 0 bf16 out, 1 f32 out, 2 fused-conv KL.
template<int MODE>
__global__ __launch_bounds__(256, 2) void k_gemm(
    const unsigned short* __restrict__ A, const unsigned short* __restrict__ Bm,
    void* __restrict__ Cp, const float* __restrict__ bias, float bias_scale,
    int M, int N, int K, int lda, int ldb, int ldc,
    long sBz, long sCz, const unsigned short* __restrict__ zeros)
{
  __shared__ unsigned short As[128 * 64];
  __shared__ unsigned short Bs[128 * 64];
  const int m0 = blockIdx.x * 128, n0 = blockIdx.y * 128;
  const unsigned short* Bz = Bm + (long)blockIdx.z * sBz;
  const int tid = threadIdx.x, wid = tid >> 6, lane = tid & 63;
  const int l15 = lane & 15, hq = lane >> 4;
  const int wr = wid >> 1, wc = wid & 1;
  f32x4 acc[4][4];
#pragma unroll
  for (int m = 0; m < 4; ++m)
#pragma unroll
    for (int n = 0; n < 4; ++n) acc[m][n] = f32x4{0.f, 0.f, 0.f, 0.f};
  const int nkt = K >> 6;
  const int wv4 = wid * 512;           // wave's element offset in each 2048-elem chunk
  const int srow = tid >> 3;           // 0..31
  const int scol = (tid & 7) * 8;      // 0..56
  for (int kt = 0; kt < nkt; ++kt){
    __syncthreads();
    if (MODE == 2){
      const int t = kt >> 3; const int ci0 = (kt & 7) << 6;
#pragma unroll
      for (int i = 0; i < 4; ++i){
        int row = srow + i * 32;
        int gr = m0 + row;
        int sl = (gr & (SEQ_L - 1)) + t - 2;
        const unsigned short* sp = ((unsigned)sl < (unsigned)SEQ_L)
            ? (A + (long)(gr + t - 2) * lda + ci0 + scol) : (zeros + scol);
        gld16(sp, As + i * 2048 + wv4);
        gld16(Bz + (long)t * 262144 + (long)(n0 + row) * ldb + ci0 + scol,
              Bs + i * 2048 + wv4);
      }
    } else {
      const int k0 = kt << 6;
#pragma unroll
      for (int i = 0; i < 4; ++i){
        int row = srow + i * 32;
        gld16(A + (long)(m0 + row) * lda + k0 + scol, As + i * 2048 + wv4);
        gld16(Bz + (long)(n0 + row) * ldb + k0 + scol, Bs + i * 2048 + wv4);
      }
    }
    __syncthreads();
#pragma unroll
    for (int ks = 0; ks < 2; ++ks){
      const int kb = ks * 32 + 8 * hq;
      bf16x8 af[4], bfr[4];
#pragma unroll
      for (int m = 0; m < 4; ++m) af[m] = ldb8(As + (wr * 64 + m * 16 + l15) * 64 + kb);
#pragma unroll
      for (int n = 0; n < 4; ++n) bfr[n] = ldb8(Bs + (wc * 64 + n * 16 + l15) * 64 + kb);
#pragma unroll
      for (int m = 0; m < 4; ++m)
#pragma unroll
        for (int n = 0; n < 4; ++n) acc[m][n] = mfma16(af[m], bfr[n], acc[m][n]);
    }
  }
  const int crow0 = m0 + wr * 64, ccol0 = n0 + wc * 64;
#pragma unroll
  for (int n = 0; n < 4; ++n){
    int col = ccol0 + n * 16 + l15;
    float bv = bias ? bias[col] * bias_scale : 0.f;
#pragma unroll
    for (int m = 0; m < 4; ++m){
      int rowb = crow0 + m * 16 + 4 * hq;
#pragma unroll
      for (int r = 0; r < 4; ++r){
        float v = acc[m][n][r] + bv;
        long off = (long)(rowb + r) * ldc + col + (long)blockIdx.z * sCz;
        if (MODE == 1) ((float*)Cp)[off] = v;
        else ((unsigned short*)Cp)[off] = f2bf(v);
      }
    }
  }
}

// ---------------- V transpose ----------------
__global__ __launch_bounds__(256) void k_transpose(const unsigned short* __restrict__ V,
                                                   unsigned short* __restrict__ Vt){
  __shared__ unsigned short t_lds[64][72];
  const int l0 = blockIdx.x * 64, d0 = blockIdx.y * 64, b = blockIdx.z;
  const int tid = threadIdx.x;
  const int rr = tid >> 3, cc = (tid & 7) * 8;
#pragma unroll
  for (int p = 0; p < 2; ++p){
    int r = rr + p * 32;
    bf16x8 v = ldb8(V + ((long)(b * SEQ_L + l0 + r)) * D_MODEL + d0 + cc);
#pragma unroll
    for (int j = 0; j < 8; ++j) t_lds[r][cc + j] = (unsigned short)v[j];
  }
  __syncthreads();
#pragma unroll
  for (int p = 0; p < 2; ++p){
    int dr = rr + p * 32;
    bf16x8 o;
#pragma unroll
    for (int j = 0; j < 8; ++j) o[j] = (short)t_lds[cc + j][dr];
    *reinterpret_cast<bf16x8*>(Vt + ((long)(b * D_MODEL + d0 + dr)) * SEQ_L + l0 + cc) = o;
  }
}

// ---------------- flash attention: ILP-scheduled, reg-prefetched ----------------
// Math identical to round 3 (verified). Schedule: per tile, issue KG+V loads first,
// QK_L from prefetched KL regs, issue next-tile KL loads, softmax_L/PV_L (covers KG/V
// latency), QK_G, softmax_G/PV_G (covers next KL latency). Tree reductions.
__global__ __launch_bounds__(256, 2) void k_attn(
    const unsigned short* __restrict__ Q, const unsigned short* __restrict__ KLp,
    const unsigned short* __restrict__ KGp, const unsigned short* __restrict__ Vt,
    unsigned short* __restrict__ X)
{
  const int lin = blockIdx.x + (blockIdx.y << 4);
  const int sw  = ((lin & 7) << 6) + (lin >> 3);
  const int qi = sw & 15, bh = sw >> 4;
  const int b = bh >> 3, hb = (bh & 7) << 6;
  const int tid = threadIdx.x, wid = tid >> 6, lane = tid & 63;
  const int l31 = lane & 31, hi = lane >> 5;
  const int q0 = qi * 128 + wid * 32;
  const long rb = (long)b * SEQ_L;

  const long qrow = (rb + q0 + l31) * D_MODEL + hb + hi * 8;
  bf16x8 qf[4];
#pragma unroll
  for (int ch = 0; ch < 4; ++ch) qf[ch] = ldb8(Q + qrow + ch * 16);

  f32x16 o_l[2], o_g[2];
#pragma unroll
  for (int dt = 0; dt < 2; ++dt){ o_l[dt] = 0.f; o_g[dt] = 0.f; }
  float m_l = -1e30f, s_l = 0.f, m_g = -1e30f, s_g = 0.f;

  const long vbase = ((long)(b * D_MODEL + hb + l31)) * SEQ_L + hi * 8;
  const long kbase0 = (rb + l31) * D_MODEL + hb + hi * 8;

  auto softmax_pv = [&](f32x16& sa, f32x16& sb, float& mrun, float& srun,
                        f32x16 (&o)[2], bf16x8 (&vf)[2][4]){
    float u[8];
#pragma unroll
    for (int r = 0; r < 8; ++r)
      u[r] = fmaxf(fmaxf(sa[r], sa[r + 8]), fmaxf(sb[r], sb[r + 8]));
    float pm = fmaxf(fmaxf(fmaxf(u[0], u[1]), fmaxf(u[2], u[3])),
                     fmaxf(fmaxf(u[4], u[5]), fmaxf(u[6], u[7])));
    i32x2 pr = __builtin_amdgcn_permlane32_swap(__float_as_int(pm), __float_as_int(pm), false, false);
    pm = fmaxf(pm, fmaxf(__int_as_float(pr[0]), __int_as_float(pr[1])));
    if (__any(pm > mrun + 11.0f)){
      float mn = fmaxf(mrun, pm);
      float rs = exp2f(mrun - mn);
      srun *= rs; mrun = mn;
#pragma unroll
      for (int r = 0; r < 16; ++r){ o[0][r] *= rs; o[1][r] *= rs; }
    }
#pragma unroll
    for (int r = 0; r < 16; ++r) sa[r] = exp2f(sa[r] - mrun);
#pragma unroll
    for (int r = 0; r < 16; ++r) sb[r] = exp2f(sb[r] - mrun);
    float w[8];
#pragma unroll
    for (int r = 0; r < 8; ++r) w[r] = (sa[r] + sa[r + 8]) + (sb[r] + sb[r + 8]);
    float sum = ((w[0] + w[1]) + (w[2] + w[3])) + ((w[4] + w[5]) + (w[6] + w[7]));
    i32x2 sr = __builtin_amdgcn_permlane32_swap(__float_as_int(sum), __float_as_int(sum), false, false);
    srun += __int_as_float(sr[0]) + __int_as_float(sr[1]);
    unsigned uu[2][4][2];
#pragma unroll
    for (int r4 = 0; r4 < 4; ++r4){
      uu[0][r4][0] = cvt_pk(sa[r4 * 4 + 0], sa[r4 * 4 + 1]);
      uu[0][r4][1] = cvt_pk(sa[r4 * 4 + 2], sa[r4 * 4 + 3]);
      uu[1][r4][0] = cvt_pk(sb[r4 * 4 + 0], sb[r4 * 4 + 1]);
      uu[1][r4][1] = cvt_pk(sb[r4 * 4 + 2], sb[r4 * 4 + 3]);
    }
#pragma unroll
    for (int kc = 0; kc < 4; ++kc){
      const int t = kc >> 1, kk = kc & 1;
      i32x2 rA = __builtin_amdgcn_permlane32_swap((int)uu[t][2 * kk][0], (int)uu[t][2 * kk + 1][0], false, false);
      i32x2 rB = __builtin_amdgcn_permlane32_swap((int)uu[t][2 * kk][1], (int)uu[t][2 * kk + 1][1], false, false);
      union { bf16x8 v; int w_[4]; } pb;
      pb.w_[0] = rA[0]; pb.w_[1] = rB[0]; pb.w_[2] = rA[1]; pb.w_[3] = rB[1];
      o[0] = mfma32(vf[0][kc], pb.v, o[0]);
      o[1] = mfma32(vf[1][kc], pb.v, o[1]);
    }
  };

  auto tile = [&](int kv, bf16x8 (&klc)[2][4], bf16x8 (&kln)[2][4]){
    const long kb0 = kbase0 + (long)kv * D_MODEL;
    const long kbn = kbase0 + (long)((kv + 64) & (SEQ_L - 1)) * D_MODEL;
    // issue cur-tile KG + V loads (consumed ~700cy later)
    bf16x8 kg[2][4], vf[2][4];
#pragma unroll
    for (int ch = 0; ch < 4; ++ch){
      kg[0][ch] = ldb8(KGp + kb0 + ch * 16);
      kg[1][ch] = ldb8(KGp + kb0 + 32 * D_MODEL + ch * 16);
    }
#pragma unroll
    for (int dt = 0; dt < 2; ++dt)
#pragma unroll
      for (int kc = 0; kc < 4; ++kc)
        vf[dt][kc] = ldb8(Vt + vbase + (long)dt * 32 * SEQ_L + kv + kc * 16);
    // QK_L from prefetched registers
    f32x16 sa = 0.f, sb = 0.f;
#pragma unroll
    for (int ch = 0; ch < 4; ++ch){
      sa = mfma32(klc[0][ch], qf[ch], sa);
      sb = mfma32(klc[1][ch], qf[ch], sb);
    }
    // prefetch next-tile KL (consumed next iteration)
#pragma unroll
    for (int ch = 0; ch < 4; ++ch){
      kln[0][ch] = ldb8(KLp + kbn + ch * 16);
      kln[1][ch] = ldb8(KLp + kbn + 32 * D_MODEL + ch * 16);
    }
    softmax_pv(sa, sb, m_l, s_l, o_l, vf);
    f32x16 ga = 0.f, gb = 0.f;
#pragma unroll
    for (int ch = 0; ch < 4; ++ch){
      ga = mfma32(kg[0][ch], qf[ch], ga);
      gb = mfma32(kg[1][ch], qf[ch], gb);
    }
    softmax_pv(ga, gb, m_g, s_g, o_g, vf);
  };

  bf16x8 klA[2][4], klB[2][4];
#pragma unroll
  for (int ch = 0; ch < 4; ++ch){
    klA[0][ch] = ldb8(KLp + kbase0 + ch * 16);
    klA[1][ch] = ldb8(KLp + kbase0 + 32 * D_MODEL + ch * 16);
  }
#pragma unroll 1
  for (int kv = 0; kv < SEQ_L; kv += 128){
    tile(kv, klA, klB);
    tile(kv + 64, klB, klA);
  }

  const float il = 1.f / s_l, ig = 1.f / s_g;
  const long xrow = (rb + q0 + l31) * D_MODEL + hb + hi * 4;
#pragma unroll
  for (int dt = 0; dt < 2; ++dt)
#pragma unroll
    for (int r4 = 0; r4 < 4; ++r4){
      float v0 = o_l[dt][r4 * 4 + 0] * il + o_g[dt][r4 * 4 + 0] * ig;
      float v1 = o_l[dt][r4 * 4 + 1] * il + o_g[dt][r4 * 4 + 1] * ig;
      float v2 = o_l[dt][r4 * 4 + 2] * il + o_g[dt][r4 * 4 + 2] * ig;
      float v3 = o_l[dt][r4 * 4 + 3] * il + o_g[dt][r4 * 4 + 3] * ig;
      uint2 pk2; pk2.x = cvt_pk(v0, v1); pk2.y = cvt_pk(v2, v3);
      *reinterpret_cast<uint2*>(X + xrow + dt * 32 + r4 * 8) = pk2;
    }
}

// ---------------- host ----------------
extern "C" void kernel_launch(void* const* d_in, const int* in_sizes, int n_in,
                              void* d_out, int out_size, void* d_ws, size_t ws_size,
                              hipStream_t stream)
{
  const float* query = (const float*)d_in[0];
  const float* key   = (const float*)d_in[1];
  const float* value = (const float*)d_in[2];
  const float* w3    = (const float*)d_in[3];
  const float* cb3   = (const float*)d_in[4];
  const float* w5    = (const float*)d_in[5];
  const float* cb5   = (const float*)d_in[6];
  const float* gamma = (const float*)d_in[7];
  const float* beta  = (const float*)d_in[8];
  const float* mean  = (const float*)d_in[9];
  const float* var   = (const float*)d_in[10];
  const float* wq    = (const float*)d_in[11];
  const float* bq    = (const float*)d_in[12];
  const float* wkl   = (const float*)d_in[13];
  const float* bkl   = (const float*)d_in[14];
  const float* wkg   = (const float*)d_in[15];
  const float* bkg   = (const float*)d_in[16];
  const float* wv    = (const float*)d_in[17];
  const float* bv    = (const float*)d_in[18];
  const float* wo    = (const float*)d_in[19];
  const float* bo    = (const float*)d_in[20];

  char* ws = (char*)d_ws;
  const size_t MB = 1024 * 1024;
  unsigned short* qb   = (unsigned short*)(ws + 0 * MB);
  unsigned short* kb   = (unsigned short*)(ws + 8 * MB);
  unsigned short* vb   = (unsigned short*)(ws + 16 * MB);
  unsigned short* Qm   = (unsigned short*)(ws + 24 * MB);
  unsigned short* KLm  = (unsigned short*)(ws + 32 * MB);
  unsigned short* KGm  = (unsigned short*)(ws + 40 * MB);
  unsigned short* Vm   = qb;   // reuse
  unsigned short* Vt   = (unsigned short*)(ws + 48 * MB);
  unsigned short* Xm   = vb;   // reuse
  unsigned short* wqb  = (unsigned short*)(ws + 56 * MB);
  unsigned short* wkgb = (unsigned short*)(ws + 56 * MB + 512 * 1024);
  unsigned short* wvb  = (unsigned short*)(ws + 57 * MB);
  unsigned short* wob  = (unsigned short*)(ws + 57 * MB + 512 * 1024);
  unsigned short* Acat = (unsigned short*)(ws + 58 * MB);
  unsigned short* Bcat = (unsigned short*)(ws + 59 * MB);
  unsigned short* Weff = (unsigned short*)(ws + 64 * MB);
  float*          beff = (float*)(ws + 67 * MB);
  unsigned short* zeros= (unsigned short*)(ws + 67 * MB + 4096);

  hipMemsetAsync(zeros, 0, 256, stream);

  const int NQKV = BLROWS * D_MODEL;
  const int NW   = D_MODEL * D_MODEL;
  dim3 tb(256);
  k_cast<<<NQKV / 1024, tb, 0, stream>>>(query, qb, NQKV, 1.f);
  k_cast<<<NQKV / 1024, tb, 0, stream>>>(key,   kb, NQKV, 1.f);
  k_cast<<<NQKV / 1024, tb, 0, stream>>>(value, vb, NQKV, 1.f);
  k_cast<<<NW / 1024, tb, 0, stream>>>(wq,  wqb,  NW, QK_SCALE);
  k_cast<<<NW / 1024, tb, 0, stream>>>(wkg, wkgb, NW, 1.f);
  k_cast<<<NW / 1024, tb, 0, stream>>>(wv,  wvb,  NW, 1.f);
  k_cast<<<NW / 1024, tb, 0, stream>>>(wo,  wob,  NW, 1.f);
  k_acat<<<(512 * 1024) / 256, tb, 0, stream>>>(wkl, gamma, var, Acat);
  k_bcat<<<(5 * 512 * 1024) / 256, tb, 0, stream>>>(w3, w5, Bcat);
  k_beff<<<2, tb, 0, stream>>>(wkl, gamma, beta, mean, var, cb3, cb5, bkl, beff);

  k_gemm<0><<<dim3(4, 4, 5), tb, 0, stream>>>(Acat, Bcat, Weff, nullptr, 0.f,
      512, 512, 1024, 1024, 1024, 512, 524288L, 262144L, nullptr);

  k_gemm<0><<<dim3(64, 4), tb, 0, stream>>>(qb, wqb, Qm, bq, QK_SCALE,
      BLROWS, D_MODEL, D_MODEL, D_MODEL, D_MODEL, D_MODEL, 0L, 0L, nullptr);
  k_gemm<2><<<dim3(64, 4), tb, 0, stream>>>(kb, Weff, KLm, beff, 1.f,
      BLROWS, D_MODEL, 2560, D_MODEL, D_MODEL, D_MODEL, 0L, 0L, zeros);
  k_gemm<0><<<dim3(64, 4), tb, 0, stream>>>(kb, wkgb, KGm, bkg, 1.f,
      BLROWS, D_MODEL, D_MODEL, D_MODEL, D_MODEL, D_MODEL, 0L, 0L, nullptr);
  k_gemm<0><<<dim3(64, 4), tb, 0, stream>>>(vb, wvb, Vm, bv, 1.f,
      BLROWS, D_MODEL, D_MODEL, D_MODEL, D_MODEL, D_MODEL, 0L, 0L, nullptr);

  k_transpose<<<dim3(32, 8, 4), tb, 0, stream>>>(Vm, Vt);
  k_attn<<<dim3(16, 32), tb, 0, stream>>>(Qm, KLm, KGm, Vt, Xm);

  k_gemm<1><<<dim3(64, 4), tb, 0, stream>>>(Xm, wob, d_out, bo, 1.f,
      BLROWS, D_MODEL, D_MODEL, D_MODEL, D_MODEL, D_MODEL, 0L, 0L, nullptr);
}

// Round 5
// 304.565 us; speedup vs baseline: 1.6955x; 1.4481x over previous
//
#include <hip/hip_runtime.h>
#include <hip/hip_bf16.h>

#define D_MODEL 512
#define SEQ_L   2048
#define NBATCH  4
#define BLROWS  8192
#define BN_EPS_F 1e-5f
#define QK_SCALE 0.18033688011112042f  /* (1/sqrt(64)) * log2(e) */

typedef __attribute__((ext_vector_type(8))) short bf16x8;
typedef __attribute__((ext_vector_type(4))) float f32x4;
typedef __attribute__((ext_vector_type(16))) float f32x16;
typedef __attribute__((ext_vector_type(2))) int i32x2;

__device__ __forceinline__ unsigned short f2bf(float f){
  union { float f; unsigned u; } x; x.f = f;
  return (unsigned short)((x.u + 0x7fffu + ((x.u >> 16) & 1u)) >> 16);
}
__device__ __forceinline__ unsigned pack2bf(float a, float b){
  return (unsigned)f2bf(a) | ((unsigned)f2bf(b) << 16);
}
__device__ __forceinline__ unsigned cvt_pk(float a, float b){
  unsigned r;
  asm("v_cvt_pk_bf16_f32 %0, %1, %2" : "=v"(r) : "v"(a), "v"(b));
  return r;
}
__device__ __forceinline__ f32x4 mfma16(bf16x8 a, bf16x8 b, f32x4 c){
  return __builtin_amdgcn_mfma_f32_16x16x32_bf16(a, b, c, 0, 0, 0);
}
__device__ __forceinline__ f32x16 mfma32(bf16x8 a, bf16x8 b, f32x16 c){
  return __builtin_amdgcn_mfma_f32_32x32x16_bf16(a, b, c, 0, 0, 0);
}
__device__ __forceinline__ bf16x8 ldb8(const unsigned short* p){
  return *reinterpret_cast<const bf16x8*>(p);
}
// async global->LDS, 16B per lane; LDS dest = wave-uniform base + lane*16
__device__ __forceinline__ void gld16(const void* g, void* l){
  __builtin_amdgcn_global_load_lds(
      (const __attribute__((address_space(1))) unsigned*)g,
      (__attribute__((address_space(3))) unsigned*)l, 16, 0, 0);
}

// ---------------- elementwise prep ----------------
__global__ void k_cast(const float* __restrict__ src, unsigned short* __restrict__ dst,
                       int n, float scale){
  int i = (blockIdx.x * blockDim.x + threadIdx.x) * 4;
  if (i >= n) return;
  float4 v = *reinterpret_cast<const float4*>(src + i);
  uint2 o;
  o.x = pack2bf(v.x * scale, v.y * scale);
  o.y = pack2bf(v.z * scale, v.w * scale);
  *reinterpret_cast<uint2*>(dst + i) = o;
}

__global__ void k_acat(const float* __restrict__ wkl, const float* __restrict__ gamma,
                       const float* __restrict__ var, unsigned short* __restrict__ Acat){
  int idx = blockIdx.x * blockDim.x + threadIdx.x;
  int o = idx >> 10, ch = idx & 1023;
  int c = (ch < 512) ? (512 + ch) : (ch - 512);
  float a = gamma[c] * rsqrtf(var[c] + BN_EPS_F);
  Acat[idx] = f2bf(wkl[o * 1024 + c] * a);
}

__global__ void k_bcat(const float* __restrict__ w3, const float* __restrict__ w5,
                       unsigned short* __restrict__ Bcat){
  int idx = blockIdx.x * blockDim.x + threadIdx.x;
  int t = idx >> 19; int r = idx & 524287;
  int ci = r >> 10, ch = r & 1023;
  float v;
  if (ch < 512) v = w5[ch * 2560 + ci * 5 + t];
  else {
    int c3 = ch - 512;
    v = (t >= 1 && t <= 3) ? w3[c3 * 1536 + ci * 3 + (t - 1)] : 0.0f;
  }
  Bcat[idx] = f2bf(v);
}

// wave-per-output reduction (was serial 1024-iter loop)
__global__ void k_beff(const float* __restrict__ wkl, const float* __restrict__ gamma,
                       const float* __restrict__ beta, const float* __restrict__ mean,
                       const float* __restrict__ var, const float* __restrict__ cb3,
                       const float* __restrict__ cb5, const float* __restrict__ bkl,
                       float* __restrict__ beff){
  const int o = blockIdx.x * 4 + (threadIdx.x >> 6);
  const int lane = threadIdx.x & 63;
  float acc = 0.f;
  for (int c = lane; c < 1024; c += 64){
    float a = gamma[c] * rsqrtf(var[c] + BN_EPS_F);
    float cb = (c < 512) ? cb3[c] : cb5[c - 512];
    acc += wkl[o * 1024 + c] * (a * cb + beta[c] - a * mean[c]);
  }
#pragma unroll
  for (int off = 32; off; off >>= 1) acc += __shfl_down(acc, off);
  if (lane == 0) beff[o] = acc + bkl[o];
}

// ---------------- GEMM with global_load_lds staging ----------------
template<int MODE>
__global__ __launch_bounds__(256, 2) void k_gemm(
    const unsigned short* __restrict__ A, const unsigned short* __restrict__ Bm,
    void* __restrict__ Cp, const float* __restrict__ bias, float bias_scale,
    int M, int N, int K, int lda, int ldb, int ldc,
    long sBz, long sCz, const unsigned short* __restrict__ zeros)
{
  __shared__ unsigned short As[128 * 64];
  __shared__ unsigned short Bs[128 * 64];
  const int m0 = blockIdx.x * 128, n0 = blockIdx.y * 128;
  const unsigned short* Bz = Bm + (long)blockIdx.z * sBz;
  const int tid = threadIdx.x, wid = tid >> 6, lane = tid & 63;
  const int l15 = lane & 15, hq = lane >> 4;
  const int wr = wid >> 1, wc = wid & 1;
  f32x4 acc[4][4];
#pragma unroll
  for (int m = 0; m < 4; ++m)
#pragma unroll
    for (int n = 0; n < 4; ++n) acc[m][n] = f32x4{0.f, 0.f, 0.f, 0.f};
  const int nkt = K >> 6;
  const int wv4 = wid * 512;
  const int srow = tid >> 3;
  const int scol = (tid & 7) * 8;
  for (int kt = 0; kt < nkt; ++kt){
    __syncthreads();
    if (MODE == 2){
      const int t = kt >> 3; const int ci0 = (kt & 7) << 6;
#pragma unroll
      for (int i = 0; i < 4; ++i){
        int row = srow + i * 32;
        int gr = m0 + row;
        int sl = (gr & (SEQ_L - 1)) + t - 2;
        const unsigned short* sp = ((unsigned)sl < (unsigned)SEQ_L)
            ? (A + (long)(gr + t - 2) * lda + ci0 + scol) : (zeros + scol);
        gld16(sp, As + i * 2048 + wv4);
        gld16(Bz + (long)t * 262144 + (long)(n0 + row) * ldb + ci0 + scol,
              Bs + i * 2048 + wv4);
      }
    } else {
      const int k0 = kt << 6;
#pragma unroll
      for (int i = 0; i < 4; ++i){
        int row = srow + i * 32;
        gld16(A + (long)(m0 + row) * lda + k0 + scol, As + i * 2048 + wv4);
        gld16(Bz + (long)(n0 + row) * ldb + k0 + scol, Bs + i * 2048 + wv4);
      }
    }
    __syncthreads();
#pragma unroll
    for (int ks = 0; ks < 2; ++ks){
      const int kb = ks * 32 + 8 * hq;
      bf16x8 af[4], bfr[4];
#pragma unroll
      for (int m = 0; m < 4; ++m) af[m] = ldb8(As + (wr * 64 + m * 16 + l15) * 64 + kb);
#pragma unroll
      for (int n = 0; n < 4; ++n) bfr[n] = ldb8(Bs + (wc * 64 + n * 16 + l15) * 64 + kb);
#pragma unroll
      for (int m = 0; m < 4; ++m)
#pragma unroll
        for (int n = 0; n < 4; ++n) acc[m][n] = mfma16(af[m], bfr[n], acc[m][n]);
    }
  }
  const int crow0 = m0 + wr * 64, ccol0 = n0 + wc * 64;
#pragma unroll
  for (int n = 0; n < 4; ++n){
    int col = ccol0 + n * 16 + l15;
    float bv = bias ? bias[col] * bias_scale : 0.f;
#pragma unroll
    for (int m = 0; m < 4; ++m){
      int rowb = crow0 + m * 16 + 4 * hq;
#pragma unroll
      for (int r = 0; r < 4; ++r){
        float v = acc[m][n][r] + bv;
        long off = (long)(rowb + r) * ldc + col + (long)blockIdx.z * sCz;
        if (MODE == 1) ((float*)Cp)[off] = v;
        else ((unsigned short*)Cp)[off] = f2bf(v);
      }
    }
  }
}

// ---------------- V transpose ----------------
__global__ __launch_bounds__(256) void k_transpose(const unsigned short* __restrict__ V,
                                                   unsigned short* __restrict__ Vt){
  __shared__ unsigned short t_lds[64][72];
  const int l0 = blockIdx.x * 64, d0 = blockIdx.y * 64, b = blockIdx.z;
  const int tid = threadIdx.x;
  const int rr = tid >> 3, cc = (tid & 7) * 8;
#pragma unroll
  for (int p = 0; p < 2; ++p){
    int r = rr + p * 32;
    bf16x8 v = ldb8(V + ((long)(b * SEQ_L + l0 + r)) * D_MODEL + d0 + cc);
#pragma unroll
    for (int j = 0; j < 8; ++j) t_lds[r][cc + j] = (unsigned short)v[j];
  }
  __syncthreads();
#pragma unroll
  for (int p = 0; p < 2; ++p){
    int dr = rr + p * 32;
    bf16x8 o;
#pragma unroll
    for (int j = 0; j < 8; ++j) o[j] = (short)t_lds[cc + j][dr];
    *reinterpret_cast<bf16x8*>(Vt + ((long)(b * D_MODEL + d0 + dr)) * SEQ_L + l0 + cc) = o;
  }
}

// ---------------- flash attention: LDS-staged K/V, double-buffered ----------------
// Math identical to round-3 kernel (verified). Fragments now come from LDS tiles
// staged cooperatively by all 4 waves (4x less L2 traffic, coalesced, pipelined).
// Swizzle (rule 21, both sides): LDS[row][cl] holds global chunk cl^(row&7);
// reader of global chunk c uses LDS chunk c^(row&7). <=4-way bank conflict.
__global__ __launch_bounds__(256, 2) void k_attn(
    const unsigned short* __restrict__ Q, const unsigned short* __restrict__ KLp,
    const unsigned short* __restrict__ KGp, const unsigned short* __restrict__ Vt,
    unsigned short* __restrict__ X)
{
  __shared__ unsigned short KLb[2][64 * 64];
  __shared__ unsigned short KGb[2][64 * 64];
  __shared__ unsigned short Vb [2][64 * 64];

  const int lin = blockIdx.x + (blockIdx.y << 4);
  const int sw  = ((lin & 7) << 6) + (lin >> 3);
  const int qi = sw & 15, bh = sw >> 4;
  const int b = bh >> 3, hb = (bh & 7) << 6;
  const int tid = threadIdx.x, wid = tid >> 6, lane = tid & 63;
  const int l31 = lane & 31, hi = lane >> 5;
  const int s7 = l31 & 7;
  const int q0 = qi * 128 + wid * 32;
  const long rb = (long)b * SEQ_L;

  const long qrow = (rb + q0 + l31) * D_MODEL + hb + hi * 8;
  bf16x8 qf[4];
#pragma unroll
  for (int ch = 0; ch < 4; ++ch) qf[ch] = ldb8(Q + qrow + ch * 16);

  f32x16 o_l[2], o_g[2];
#pragma unroll
  for (int dt = 0; dt < 2; ++dt){ o_l[dt] = 0.f; o_g[dt] = 0.f; }
  float m_l = -1e30f, s_l = 0.f, m_g = -1e30f, s_g = 0.f;

  // stage one 64x64 bf16 tile: gbase points at (row0,col0); rowstride in elems
  auto stage = [&](const unsigned short* gbase, long rowstride, unsigned short* lb){
#pragma unroll
    for (int i = 0; i < 2; ++i){
      const int idx0 = (i * 4 + wid) * 64;          // wave-uniform chunk base
      const int idx = idx0 + lane;                  // this lane's chunk
      const int row = idx >> 3, cl = idx & 7;
      const int cg = cl ^ (row & 7);                // pre-swizzled global source
      gld16(gbase + (long)row * rowstride + cg * 8, lb + idx0 * 8);
    }
  };

  auto qk = [&](const unsigned short* Kb_, f32x16& sa, f32x16& sb){
#pragma unroll
    for (int ch = 0; ch < 4; ++ch){
      bf16x8 k0 = ldb8(Kb_ + l31 * 64 + (((hi + 2 * ch) ^ s7) * 8));
      bf16x8 k1 = ldb8(Kb_ + (l31 + 32) * 64 + (((hi + 2 * ch) ^ s7) * 8));
      sa = mfma32(k0, qf[ch], sa);
      sb = mfma32(k1, qf[ch], sb);
    }
  };

  auto softmax_pv = [&](f32x16& sa, f32x16& sb, float& mrun, float& srun,
                        f32x16 (&o)[2], bf16x8 (&vf)[2][4]){
    float u[8];
#pragma unroll
    for (int r = 0; r < 8; ++r)
      u[r] = fmaxf(fmaxf(sa[r], sa[r + 8]), fmaxf(sb[r], sb[r + 8]));
    float pm = fmaxf(fmaxf(fmaxf(u[0], u[1]), fmaxf(u[2], u[3])),
                     fmaxf(fmaxf(u[4], u[5]), fmaxf(u[6], u[7])));
    i32x2 pr = __builtin_amdgcn_permlane32_swap(__float_as_int(pm), __float_as_int(pm), false, false);
    pm = fmaxf(pm, fmaxf(__int_as_float(pr[0]), __int_as_float(pr[1])));
    if (__any(pm > mrun + 11.0f)){
      float mn = fmaxf(mrun, pm);
      float rs = exp2f(mrun - mn);
      srun *= rs; mrun = mn;
#pragma unroll
      for (int r = 0; r < 16; ++r){ o[0][r] *= rs; o[1][r] *= rs; }
    }
#pragma unroll
    for (int r = 0; r < 16; ++r) sa[r] = exp2f(sa[r] - mrun);
#pragma unroll
    for (int r = 0; r < 16; ++r) sb[r] = exp2f(sb[r] - mrun);
    float w[8];
#pragma unroll
    for (int r = 0; r < 8; ++r) w[r] = (sa[r] + sa[r + 8]) + (sb[r] + sb[r + 8]);
    float sum = ((w[0] + w[1]) + (w[2] + w[3])) + ((w[4] + w[5]) + (w[6] + w[7]));
    i32x2 sr = __builtin_amdgcn_permlane32_swap(__float_as_int(sum), __float_as_int(sum), false, false);
    srun += __int_as_float(sr[0]) + __int_as_float(sr[1]);
    unsigned uu[2][4][2];
#pragma unroll
    for (int r4 = 0; r4 < 4; ++r4){
      uu[0][r4][0] = cvt_pk(sa[r4 * 4 + 0], sa[r4 * 4 + 1]);
      uu[0][r4][1] = cvt_pk(sa[r4 * 4 + 2], sa[r4 * 4 + 3]);
      uu[1][r4][0] = cvt_pk(sb[r4 * 4 + 0], sb[r4 * 4 + 1]);
      uu[1][r4][1] = cvt_pk(sb[r4 * 4 + 2], sb[r4 * 4 + 3]);
    }
#pragma unroll
    for (int kc = 0; kc < 4; ++kc){
      const int t = kc >> 1, kk = kc & 1;
      i32x2 rA = __builtin_amdgcn_permlane32_swap((int)uu[t][2 * kk][0], (int)uu[t][2 * kk + 1][0], false, false);
      i32x2 rB = __builtin_amdgcn_permlane32_swap((int)uu[t][2 * kk][1], (int)uu[t][2 * kk + 1][1], false, false);
      union { bf16x8 v; int w_[4]; } pb;
      pb.w_[0] = rA[0]; pb.w_[1] = rB[0]; pb.w_[2] = rA[1]; pb.w_[3] = rB[1];
      o[0] = mfma32(vf[0][kc], pb.v, o[0]);
      o[1] = mfma32(vf[1][kc], pb.v, o[1]);
    }
  };

  const unsigned short* klg = KLp + rb * D_MODEL + hb;
  const unsigned short* kgg = KGp + rb * D_MODEL + hb;
  const unsigned short* vtg = Vt + ((long)b * D_MODEL + hb) * SEQ_L;

  stage(klg, D_MODEL, KLb[0]);
  stage(kgg, D_MODEL, KGb[0]);
  stage(vtg, SEQ_L,  Vb[0]);
  asm volatile("s_waitcnt vmcnt(0)" ::: "memory");
  __syncthreads();

  int cur = 0;
#pragma unroll 1
  for (int t = 0; t < SEQ_L / 64; ++t){
    const int nxt = cur ^ 1;
    if (t < SEQ_L / 64 - 1){
      const long kvn = (long)(t + 1) * 64;
      stage(klg + kvn * D_MODEL, D_MODEL, KLb[nxt]);
      stage(kgg + kvn * D_MODEL, D_MODEL, KGb[nxt]);
      stage(vtg + kvn,           SEQ_L,   Vb[nxt]);
    }
    bf16x8 vf[2][4];
#pragma unroll
    for (int dt = 0; dt < 2; ++dt)
#pragma unroll
      for (int kc = 0; kc < 4; ++kc)
        vf[dt][kc] = ldb8(Vb[cur] + (l31 + dt * 32) * 64 + (((kc * 2 + hi) ^ s7) * 8));
    f32x16 sa = 0.f, sb = 0.f;
    qk(KLb[cur], sa, sb);
    softmax_pv(sa, sb, m_l, s_l, o_l, vf);
    f32x16 ga = 0.f, gb = 0.f;
    qk(KGb[cur], ga, gb);
    softmax_pv(ga, gb, m_g, s_g, o_g, vf);
    asm volatile("s_waitcnt vmcnt(0)" ::: "memory");
    __syncthreads();
    cur = nxt;
  }

  const float il = 1.f / s_l, ig = 1.f / s_g;
  const long xrow = (rb + q0 + l31) * D_MODEL + hb + hi * 4;
#pragma unroll
  for (int dt = 0; dt < 2; ++dt)
#pragma unroll
    for (int r4 = 0; r4 < 4; ++r4){
      float v0 = o_l[dt][r4 * 4 + 0] * il + o_g[dt][r4 * 4 + 0] * ig;
      float v1 = o_l[dt][r4 * 4 + 1] * il + o_g[dt][r4 * 4 + 1] * ig;
      float v2 = o_l[dt][r4 * 4 + 2] * il + o_g[dt][r4 * 4 + 2] * ig;
      float v3 = o_l[dt][r4 * 4 + 3] * il + o_g[dt][r4 * 4 + 3] * ig;
      uint2 pk2; pk2.x = cvt_pk(v0, v1); pk2.y = cvt_pk(v2, v3);
      *reinterpret_cast<uint2*>(X + xrow + dt * 32 + r4 * 8) = pk2;
    }
}

// ---------------- host ----------------
extern "C" void kernel_launch(void* const* d_in, const int* in_sizes, int n_in,
                              void* d_out, int out_size, void* d_ws, size_t ws_size,
                              hipStream_t stream)
{
  const float* query = (const float*)d_in[0];
  const float* key   = (const float*)d_in[1];
  const float* value = (const float*)d_in[2];
  const float* w3    = (const float*)d_in[3];
  const float* cb3   = (const float*)d_in[4];
  const float* w5    = (const float*)d_in[5];
  const float* cb5   = (const float*)d_in[6];
  const float* gamma = (const float*)d_in[7];
  const float* beta  = (const float*)d_in[8];
  const float* mean  = (const float*)d_in[9];
  const float* var   = (const float*)d_in[10];
  const float* wq    = (const float*)d_in[11];
  const float* bq    = (const float*)d_in[12];
  const float* wkl   = (const float*)d_in[13];
  const float* bkl   = (const float*)d_in[14];
  const float* wkg   = (const float*)d_in[15];
  const float* bkg   = (const float*)d_in[16];
  const float* wv    = (const float*)d_in[17];
  const float* bv    = (const float*)d_in[18];
  const float* wo    = (const float*)d_in[19];
  const float* bo    = (const float*)d_in[20];

  char* ws = (char*)d_ws;
  const size_t MB = 1024 * 1024;
  unsigned short* qb   = (unsigned short*)(ws + 0 * MB);
  unsigned short* kb   = (unsigned short*)(ws + 8 * MB);
  unsigned short* vb   = (unsigned short*)(ws + 16 * MB);
  unsigned short* Qm   = (unsigned short*)(ws + 24 * MB);
  unsigned short* KLm  = (unsigned short*)(ws + 32 * MB);
  unsigned short* KGm  = (unsigned short*)(ws + 40 * MB);
  unsigned short* Vm   = qb;   // reuse
  unsigned short* Vt   = (unsigned short*)(ws + 48 * MB);
  unsigned short* Xm   = vb;   // reuse
  unsigned short* wqb  = (unsigned short*)(ws + 56 * MB);
  unsigned short* wkgb = (unsigned short*)(ws + 56 * MB + 512 * 1024);
  unsigned short* wvb  = (unsigned short*)(ws + 57 * MB);
  unsigned short* wob  = (unsigned short*)(ws + 57 * MB + 512 * 1024);
  unsigned short* Acat = (unsigned short*)(ws + 58 * MB);
  unsigned short* Bcat = (unsigned short*)(ws + 59 * MB);
  unsigned short* Weff = (unsigned short*)(ws + 64 * MB);
  float*          beff = (float*)(ws + 67 * MB);
  unsigned short* zeros= (unsigned short*)(ws + 67 * MB + 4096);

  hipMemsetAsync(zeros, 0, 256, stream);

  const int NQKV = BLROWS * D_MODEL;
  const int NW   = D_MODEL * D_MODEL;
  dim3 tb(256);
  k_cast<<<NQKV / 1024, tb, 0, stream>>>(query, qb, NQKV, 1.f);
  k_cast<<<NQKV / 1024, tb, 0, stream>>>(key,   kb, NQKV, 1.f);
  k_cast<<<NQKV / 1024, tb, 0, stream>>>(value, vb, NQKV, 1.f);
  k_cast<<<NW / 1024, tb, 0, stream>>>(wq,  wqb,  NW, QK_SCALE);
  k_cast<<<NW / 1024, tb, 0, stream>>>(wkg, wkgb, NW, 1.f);
  k_cast<<<NW / 1024, tb, 0, stream>>>(wv,  wvb,  NW, 1.f);
  k_cast<<<NW / 1024, tb, 0, stream>>>(wo,  wob,  NW, 1.f);
  k_acat<<<(512 * 1024) / 256, tb, 0, stream>>>(wkl, gamma, var, Acat);
  k_bcat<<<(5 * 512 * 1024) / 256, tb, 0, stream>>>(w3, w5, Bcat);
  k_beff<<<128, tb, 0, stream>>>(wkl, gamma, beta, mean, var, cb3, cb5, bkl, beff);

  k_gemm<0><<<dim3(4, 4, 5), tb, 0, stream>>>(Acat, Bcat, Weff, nullptr, 0.f,
      512, 512, 1024, 1024, 1024, 512, 524288L, 262144L, nullptr);

  k_gemm<0><<<dim3(64, 4), tb, 0, stream>>>(qb, wqb, Qm, bq, QK_SCALE,
      BLROWS, D_MODEL, D_MODEL, D_MODEL, D_MODEL, D_MODEL, 0L, 0L, nullptr);
  k_gemm<2><<<dim3(64, 4), tb, 0, stream>>>(kb, Weff, KLm, beff, 1.f,
      BLROWS, D_MODEL, 2560, D_MODEL, D_MODEL, D_MODEL, 0L, 0L, zeros);
  k_gemm<0><<<dim3(64, 4), tb, 0, stream>>>(kb, wkgb, KGm, bkg, 1.f,
      BLROWS, D_MODEL, D_MODEL, D_MODEL, D_MODEL, D_MODEL, 0L, 0L, nullptr);
  k_gemm<0><<<dim3(64, 4), tb, 0, stream>>>(vb, wvb, Vm, bv, 1.f,
      BLROWS, D_MODEL, D_MODEL, D_MODEL, D_MODEL, D_MODEL, 0L, 0L, nullptr);

  k_transpose<<<dim3(32, 8, 4), tb, 0, stream>>>(Vm, Vt);
  k_attn<<<dim3(16, 32), tb, 0, stream>>>(Qm, KLm, KGm, Vt, Xm);

  k_gemm<1><<<dim3(64, 4), tb, 0, stream>>>(Xm, wob, d_out, bo, 1.f,
      BLROWS, D_MODEL, D_MODEL, D_MODEL, D_MODEL, D_MODEL, 0L, 0L, nullptr);
}